// Round 11
// baseline (431.694 us; speedup 1.0000x reference)
//
#include <hip/hip_runtime.h>
#include <float.h>
#include <math.h>

#define B_ 16
#define N_ 128
#define C_ 768
#define G_ 2000
#define CK_ 100
#define ALPHA_ 0.6f
#define EPS_ 1e-12f

typedef __attribute__((ext_vector_type(8))) short bf16x8;
typedef __attribute__((ext_vector_type(16))) float f32x16;

// ---------------- helpers ----------------
__device__ inline float wave_sum_lane0(float s) {
  #pragma unroll
  for (int off = 32; off > 0; off >>= 1) s += __shfl_down(s, off);
  return s;  // valid in lane 0
}
__device__ inline float wave_sum_all(float s) {
  #pragma unroll
  for (int off = 1; off < 64; off <<= 1) s += __shfl_xor(s, off);
  return s;
}

__device__ inline unsigned short bf16_rtn(float x) {
  unsigned u = __float_as_uint(x);
  u += 0x7fffu + ((u >> 16) & 1u);
  return (unsigned short)(u >> 16);
}
// split one float into hi/lo bf16 (RNE) — validated R2 rounding path
__device__ inline void split2(float x, unsigned short& h, unsigned short& l) {
  h = bf16_rtn(x);
  float r = x - __uint_as_float(((unsigned)h) << 16);
  l = bf16_rtn(r);
}
// 8 consecutive floats -> packed hi uint4 + lo uint4 (RNE), accumulating sq-sum
__device__ inline void csplit8(const float4& v0, const float4& v1,
                               uint4& h, uint4& l, float& sq) {
  float f[8] = {v0.x, v0.y, v0.z, v0.w, v1.x, v1.y, v1.z, v1.w};
  unsigned short hh[8], ll[8];
  #pragma unroll
  for (int i = 0; i < 8; ++i) {
    float x = f[i];
    sq = fmaf(x, x, sq);
    split2(x, hh[i], ll[i]);
  }
  h.x = (unsigned)hh[0] | ((unsigned)hh[1] << 16);
  h.y = (unsigned)hh[2] | ((unsigned)hh[3] << 16);
  h.z = (unsigned)hh[4] | ((unsigned)hh[5] << 16);
  h.w = (unsigned)hh[6] | ((unsigned)hh[7] << 16);
  l.x = (unsigned)ll[0] | ((unsigned)ll[1] << 16);
  l.y = (unsigned)ll[2] | ((unsigned)ll[3] << 16);
  l.z = (unsigned)ll[4] | ((unsigned)ll[5] << 16);
  l.w = (unsigned)ll[6] | ((unsigned)ll[7] << 16);
}

// ---------------- fused prep: cls cosine distances + query patch norm/split ----------------
#define NCLSBLK_ (B_ * G_ / 4)
__global__ void prep_kernel(const float* __restrict__ gcls, const float* __restrict__ qcls,
                            const float* __restrict__ qp,
                            float* __restrict__ dall,
                            unsigned short* __restrict__ qhi, unsigned short* __restrict__ qlo) {
  int t = threadIdx.x;
  int lane = t & 63;
  if ((int)blockIdx.x < NCLSBLK_) {
    int id = ((int)blockIdx.x * 256 + t) >> 6;
    int b = id / G_, g = id - b * G_;
    const float4* gv = (const float4*)(gcls + (size_t)g * C_);
    const float4* qv = (const float4*)(qcls + (size_t)b * C_);
    float sgq = 0.f, sgg = 0.f, sqq = 0.f;
    #pragma unroll
    for (int i = 0; i < 3; ++i) {
      float4 x = gv[lane + 64 * i], y = qv[lane + 64 * i];
      sgq += x.x * y.x + x.y * y.y + x.z * y.z + x.w * y.w;
      sgg += x.x * x.x + x.y * x.y + x.z * x.z + x.w * x.w;
      sqq += y.x * y.x + y.y * y.y + y.z * y.z + y.w * y.w;
    }
    sgq = wave_sum_lane0(sgq);
    sgg = wave_sum_lane0(sgg);
    sqq = wave_sum_lane0(sqq);
    if (lane == 0) {
      float gi = 1.0f / fmaxf(sqrtf(sgg), EPS_);
      float qi = 1.0f / fmaxf(sqrtf(sqq), EPS_);
      dall[id] = sgq * gi * qi;
    }
  } else {
    int wid = (((int)blockIdx.x - NCLSBLK_) * 256 + t) >> 6;
    const float4* v = (const float4*)(qp + (size_t)wid * C_);
    float4 x0 = v[lane], x1 = v[lane + 64], x2 = v[lane + 128];
    float s = x0.x * x0.x + x0.y * x0.y + x0.z * x0.z + x0.w * x0.w
            + x1.x * x1.x + x1.y * x1.y + x1.z * x1.z + x1.w * x1.w
            + x2.x * x2.x + x2.y * x2.y + x2.z * x2.z + x2.w * x2.w;
    s = wave_sum_all(s);
    float inv = 1.0f / fmaxf(sqrtf(s), EPS_);
    float4 xs[3] = {x0, x1, x2};
    #pragma unroll
    for (int i = 0; i < 3; ++i) {
      float4 x = xs[i];
      x.x *= inv; x.y *= inv; x.z *= inv; x.w *= inv;
      ushort4 h, l;
      split2(x.x, h.x, l.x); split2(x.y, h.y, l.y);
      split2(x.z, h.z, l.z); split2(x.w, h.w, l.w);
      size_t off = (size_t)wid * C_ + (size_t)(lane + 64 * i) * 4;
      *(ushort4*)(qhi + off) = h;
      *(ushort4*)(qlo + off) = l;
    }
  }
}

// ---------------- top-100 per sample via full bitonic sort of 2048 packed keys -------------
__global__ void top100_kernel(const float* __restrict__ dall, int* __restrict__ cls_idx,
                              float* __restrict__ dsel) {
  __shared__ unsigned long long s[2048];
  int b = blockIdx.x, t = threadIdx.x;
  for (int i = t; i < 2048; i += 256) {
    unsigned long long y = 0xFFFFFFFFFFFFFFFFull;
    if (i < G_) {
      unsigned u = __float_as_uint(dall[b * G_ + i]);
      unsigned key = (u & 0x80000000u) ? ~u : (u | 0x80000000u);
      y = ~(((unsigned long long)key << 32) | (unsigned long long)(0xFFFFFFFFu - (unsigned)i));
    }
    s[i] = y;
  }
  __syncthreads();
  for (int k = 2; k <= 2048; k <<= 1) {
    for (int j = k >> 1; j > 0; j >>= 1) {
      for (int i = t; i < 2048; i += 256) {
        int l = i ^ j;
        if (l > i) {
          unsigned long long a = s[i], c = s[l];
          bool up = ((i & k) == 0);
          if ((a > c) == up) { s[i] = c; s[l] = a; }
        }
      }
      __syncthreads();
    }
  }
  for (int it = t; it < CK_; it += 256) {
    unsigned long long x = ~s[it];
    int idx = (int)(0xFFFFFFFFu - (unsigned)(x & 0xFFFFFFFFull));
    unsigned key = (unsigned)(x >> 32);
    unsigned u = (key & 0x80000000u) ? (key & 0x7FFFFFFFu) : ~key;
    cls_idx[b * CK_ + it] = idx;
    dsel[b * CK_ + it] = __uint_as_float(u);
  }
}

// ---------------- EMD kernel: DIAGNOSTIC twin-block probe -----------------------------------
// R8-validated structure. Grid is 2x; twins (xc,2q) and (xc,2q+1) compute the SAME (b,k) and
// write identical dist values (benign). Twins are 8 blockIdx apart -> same dispatch round &
// XCD -> if HBM-bound the twin rides L2/MSHR (total ~unchanged); if compute-bound total grows
// by ~T_emd and the doubled dispatch surfaces in the rocprof top-5 with counters.
__global__ __launch_bounds__(256, 2) void emd_kernel(
    const unsigned short* __restrict__ qhi, const unsigned short* __restrict__ qlo,
    const float* __restrict__ gpat,
    const int* __restrict__ cls_idx, const float* __restrict__ dsel,
    float* __restrict__ dist) {
  __shared__ __align__(16) unsigned short sAhi[4096], sAlo[4096], sBhi[4096], sBlo[4096];
  __shared__ float red_row[128][2];
  __shared__ float red_col[128][2];
  __shared__ float bss[256];
  __shared__ float binv[128];

  int r = blockIdx.x;                   // 0..3199
  int xc = r & 7;
  int q2 = r >> 3;                      // 0..399
  int q = q2 >> 1;                      // twin pairs adjacent -> same XCD, same round
  int b = 2 * xc + (q >= CK_ ? 1 : 0);
  int k = (q >= CK_) ? (q - CK_) : q;
  int blk = b * CK_ + k;
  int g = cls_idx[blk];

  const float* Bptr = gpat + (size_t)g * (N_ * C_);

  int t = threadIdx.x;
  int lane = t & 63, wv = t >> 6;
  int wr = wv >> 1, wc = wv & 1;
  int l31 = lane & 31, lhi = lane >> 5;

  int m_st = t >> 1, half = t & 1;
  const unsigned short* ahB = qhi + (size_t)(b * N_ + m_st) * C_ + half * 16;
  const unsigned short* alB = qlo + (size_t)(b * N_ + m_st) * C_ + half * 16;
  const float* bB = Bptr + (size_t)m_st * C_ + half * 16;
  int sw_st = (m_st >> 1) & 3;
  int e0 = m_st * 32 + (((2 * half + 0) ^ sw_st) << 3);
  int e1 = m_st * 32 + (((2 * half + 1) ^ sw_st) << 3);

  f32x16 acc00, acc01, acc10, acc11;
  #pragma unroll
  for (int e = 0; e < 16; ++e) { acc00[e] = 0.f; acc01[e] = 0.f; acc10[e] = 0.f; acc11[e] = 0.f; }

  int rA0 = 64 * wr + l31, rA1 = rA0 + 32;
  int rB0 = 64 * wc + l31, rB1 = rB0 + 32;
  int swF = (l31 >> 1) & 3;

  const int NT = C_ / 32;

  uint4 cah0, cah1, cal0, cal1;
  float4 cx0, cx1, cx2, cx3, cy0, cy1, cy2, cy3;
  cah0 = *(const uint4*)(ahB);      cah1 = *(const uint4*)(ahB + 8);
  cal0 = *(const uint4*)(alB);      cal1 = *(const uint4*)(alB + 8);
  cx0 = *(const float4*)(bB);       cx1 = *(const float4*)(bB + 4);
  cx2 = *(const float4*)(bB + 8);   cx3 = *(const float4*)(bB + 12);
  cy0 = *(const float4*)(bB + 32);  cy1 = *(const float4*)(bB + 36);
  cy2 = *(const float4*)(bB + 40);  cy3 = *(const float4*)(bB + 44);

  float bsq = 0.f;

#define MFMA_PHASE()                                                         \
  _Pragma("unroll")                                                          \
  for (int ks = 0; ks < 2; ++ks) {                                           \
    int so = (((ks * 2 + lhi) ^ swF) << 3);                                  \
    bf16x8 ah0 = *(const bf16x8*)&sAhi[rA0 * 32 + so];                       \
    bf16x8 al0 = *(const bf16x8*)&sAlo[rA0 * 32 + so];                       \
    bf16x8 ah1 = *(const bf16x8*)&sAhi[rA1 * 32 + so];                       \
    bf16x8 al1 = *(const bf16x8*)&sAlo[rA1 * 32 + so];                       \
    bf16x8 bh0 = *(const bf16x8*)&sBhi[rB0 * 32 + so];                       \
    bf16x8 bl0 = *(const bf16x8*)&sBlo[rB0 * 32 + so];                       \
    bf16x8 bh1 = *(const bf16x8*)&sBhi[rB1 * 32 + so];                       \
    bf16x8 bl1 = *(const bf16x8*)&sBlo[rB1 * 32 + so];                       \
    acc00 = __builtin_amdgcn_mfma_f32_32x32x16_bf16(ah0, bh0, acc00, 0, 0, 0); \
    acc00 = __builtin_amdgcn_mfma_f32_32x32x16_bf16(ah0, bl0, acc00, 0, 0, 0); \
    acc00 = __builtin_amdgcn_mfma_f32_32x32x16_bf16(al0, bh0, acc00, 0, 0, 0); \
    acc01 = __builtin_amdgcn_mfma_f32_32x32x16_bf16(ah0, bh1, acc01, 0, 0, 0); \
    acc01 = __builtin_amdgcn_mfma_f32_32x32x16_bf16(ah0, bl1, acc01, 0, 0, 0); \
    acc01 = __builtin_amdgcn_mfma_f32_32x32x16_bf16(al0, bh1, acc01, 0, 0, 0); \
    acc10 = __builtin_amdgcn_mfma_f32_32x32x16_bf16(ah1, bh0, acc10, 0, 0, 0); \
    acc10 = __builtin_amdgcn_mfma_f32_32x32x16_bf16(ah1, bl0, acc10, 0, 0, 0); \
    acc10 = __builtin_amdgcn_mfma_f32_32x32x16_bf16(al1, bh0, acc10, 0, 0, 0); \
    acc11 = __builtin_amdgcn_mfma_f32_32x32x16_bf16(ah1, bh1, acc11, 0, 0, 0); \
    acc11 = __builtin_amdgcn_mfma_f32_32x32x16_bf16(ah1, bl1, acc11, 0, 0, 0); \
    acc11 = __builtin_amdgcn_mfma_f32_32x32x16_bf16(al1, bh1, acc11, 0, 0, 0); \
  }

#define TILE_PHASE(B0, B1, B2, B3, A_NEXT, B_FAR)                            \
  {                                                                          \
    __syncthreads();                                                         \
    *(uint4*)&sAhi[e0] = cah0;  *(uint4*)&sAhi[e1] = cah1;                   \
    *(uint4*)&sAlo[e0] = cal0;  *(uint4*)&sAlo[e1] = cal1;                   \
    uint4 h, l;                                                              \
    csplit8(B0, B1, h, l, bsq);                                              \
    *(uint4*)&sBhi[e0] = h;  *(uint4*)&sBlo[e0] = l;                         \
    csplit8(B2, B3, h, l, bsq);                                              \
    *(uint4*)&sBhi[e1] = h;  *(uint4*)&sBlo[e1] = l;                         \
    if ((A_NEXT) < NT) {                                                     \
      int oA = (A_NEXT) * 32;                                                \
      cah0 = *(const uint4*)(ahB + oA);  cah1 = *(const uint4*)(ahB + oA + 8); \
      cal0 = *(const uint4*)(alB + oA);  cal1 = *(const uint4*)(alB + oA + 8); \
    }                                                                        \
    if ((B_FAR) < NT) {                                                      \
      int oB = (B_FAR) * 32;                                                 \
      B0 = *(const float4*)(bB + oB);      B1 = *(const float4*)(bB + oB + 4); \
      B2 = *(const float4*)(bB + oB + 8);  B3 = *(const float4*)(bB + oB + 12);\
    }                                                                        \
    __syncthreads();                                                         \
    MFMA_PHASE();                                                            \
  }

  for (int kt = 0; kt < NT; kt += 2) {
    TILE_PHASE(cx0, cx1, cx2, cx3, kt + 1, kt + 2)   // tile kt   (even)
    TILE_PHASE(cy0, cy1, cy2, cy3, kt + 2, kt + 3)   // tile kt+1 (odd)
  }
#undef TILE_PHASE
#undef MFMA_PHASE

  bss[t] = bsq;
  __syncthreads();
  if (t < 128) {
    float s = bss[2 * t] + bss[2 * t + 1];
    binv[t] = 1.0f / fmaxf(sqrtf(s), EPS_);
  }
  __syncthreads();
  float bi0 = binv[64 * wc + l31];
  float bi1 = binv[64 * wc + 32 + l31];

  {
    float rm[16];
    #pragma unroll
    for (int e = 0; e < 16; ++e) rm[e] = fmaxf(acc00[e] * bi0, acc01[e] * bi1);
    #pragma unroll
    for (int msk = 1; msk <= 16; msk <<= 1)
      #pragma unroll
      for (int e = 0; e < 16; ++e) rm[e] = fmaxf(rm[e], __shfl_xor(rm[e], msk));
    if (l31 == 0) {
      #pragma unroll
      for (int e = 0; e < 16; ++e)
        red_row[64 * wr + (e & 3) + 8 * (e >> 2) + 4 * lhi][wc] = rm[e];
    }
  }
  {
    float rm[16];
    #pragma unroll
    for (int e = 0; e < 16; ++e) rm[e] = fmaxf(acc10[e] * bi0, acc11[e] * bi1);
    #pragma unroll
    for (int msk = 1; msk <= 16; msk <<= 1)
      #pragma unroll
      for (int e = 0; e < 16; ++e) rm[e] = fmaxf(rm[e], __shfl_xor(rm[e], msk));
    if (l31 == 0) {
      #pragma unroll
      for (int e = 0; e < 16; ++e)
        red_row[64 * wr + 32 + (e & 3) + 8 * (e >> 2) + 4 * lhi][wc] = rm[e];
    }
  }
  {
    float cm0 = -FLT_MAX, cm1 = -FLT_MAX;
    #pragma unroll
    for (int e = 0; e < 16; ++e) {
      cm0 = fmaxf(cm0, fmaxf(acc00[e], acc10[e]));
      cm1 = fmaxf(cm1, fmaxf(acc01[e], acc11[e]));
    }
    cm0 = fmaxf(cm0, __shfl_xor(cm0, 32)) * bi0;
    cm1 = fmaxf(cm1, __shfl_xor(cm1, 32)) * bi1;
    if (lane < 32) {
      red_col[64 * wc + lane][wr] = cm0;
      red_col[64 * wc + 32 + lane][wr] = cm1;
    }
  }
  __syncthreads();
  if (t < 128)
    bss[t] = fmaxf(red_row[t][0], red_row[t][1]) + fmaxf(red_col[t][0], red_col[t][1]);
  __syncthreads();
  if (t < 64) {
    float v = bss[t] + bss[t + 64];
    #pragma unroll
    for (int off = 32; off > 0; off >>= 1) v += __shfl_down(v, off);
    if (t == 0) {
      float emd = 0.5f * v * (1.0f / 128.0f);
      dist[blk] = ALPHA_ * dsel[blk] + (1.0f - ALPHA_) * emd;
    }
  }
}

// ---------------- final top-k (wave-parallel argmax) + cls mean ----------------
__global__ void sel10_kernel(const float* __restrict__ dist, const int* __restrict__ cls_idx,
                             const float* __restrict__ gcls, float* __restrict__ out_cls,
                             int* __restrict__ nb, int TK) {
  int b = blockIdx.x, t = threadIdx.x;
  __shared__ float v[128];
  __shared__ int snb[64];
  if (t < 128) v[t] = (t < CK_) ? dist[b * CK_ + t] : -FLT_MAX;
  __syncthreads();
  for (int j = 0; j < TK; ++j) {
    if (t < 64) {
      float v0 = v[t], v1 = v[t + 64];
      float bv; int bi;
      if (v0 >= v1) { bv = v0; bi = t; } else { bv = v1; bi = t + 64; }
      #pragma unroll
      for (int off = 1; off < 64; off <<= 1) {
        float ov = __shfl_xor(bv, off);
        int   oi = __shfl_xor(bi, off);
        if (ov > bv || (ov == bv && oi < bi)) { bv = ov; bi = oi; }
      }
      if (t == 0) {
        int gg = cls_idx[b * CK_ + bi];
        snb[j] = gg;
        nb[b * TK + j] = gg;
        v[bi] = -FLT_MAX;
      }
    }
    __syncthreads();
  }
  float invk = 1.0f / (float)TK;
  for (int c = t; c < C_; c += 256) {
    float s = 0.f;
    for (int j = 0; j < TK; ++j) s += gcls[(size_t)snb[j] * C_ + c];
    out_cls[(size_t)b * C_ + c] = s * invk;
  }
}

// ---------------- gather selected patches to output ----------------
__global__ void gather_kernel(const float* __restrict__ gpat, const int* __restrict__ nb,
                              float* __restrict__ out, int TK) {
  int i = blockIdx.x * blockDim.x + threadIdx.x;
  int per_vec = N_ * C_ / 4;       // float4s per gallery entry
  int per_b = TK * per_vec;
  int total = B_ * per_b;
  if (i >= total) return;
  int b = i / per_b;
  int r = i - b * per_b;
  int j = r / per_vec;
  int off = r - j * per_vec;
  int g = nb[b * TK + j];
  ((float4*)out)[i] = ((const float4*)gpat)[(size_t)g * per_vec + off];
}

extern "C" void kernel_launch(void* const* d_in, const int* in_sizes, int n_in,
                              void* d_out, int out_size, void* d_ws, size_t ws_size,
                              hipStream_t stream) {
  (void)in_sizes; (void)n_in; (void)ws_size;
  const float* qcls = (const float*)d_in[0];
  const float* qpat = (const float*)d_in[1];
  const float* gcls = (const float*)d_in[2];
  const float* gpat = (const float*)d_in[3];
  int TK = (out_size / B_ - C_) / (N_ * C_);  // = top_k (10)

  unsigned short* qhi = (unsigned short*)d_ws;               // B*N*C bf16 hi
  unsigned short* qlo = qhi + (size_t)B_ * N_ * C_;          // B*N*C bf16 lo
  float* dall  = (float*)(qlo + (size_t)B_ * N_ * C_);       // B*G
  float* dsel  = dall + B_ * G_;                             // B*CK
  float* dist  = dsel + B_ * CK_;                            // B*CK
  int* cls_idx = (int*)(dist + B_ * CK_);                    // B*CK
  int* nb      = cls_idx + B_ * CK_;                         // B*TK

  hipLaunchKernelGGL(prep_kernel, dim3(NCLSBLK_ + B_ * N_ / 4), dim3(256), 0, stream,
                     gcls, qcls, qpat, dall, qhi, qlo);
  hipLaunchKernelGGL(top100_kernel, dim3(B_), dim3(256), 0, stream, dall, cls_idx, dsel);
  hipLaunchKernelGGL(emd_kernel, dim3(B_ * CK_ * 2), dim3(256), 0, stream,
                     qhi, qlo, gpat, cls_idx, dsel, dist);
  float* out_cls = (float*)d_out + (size_t)B_ * TK * N_ * C_;
  hipLaunchKernelGGL(sel10_kernel, dim3(B_), dim3(256), 0, stream,
                     dist, cls_idx, gcls, out_cls, nb, TK);
  int total4 = B_ * TK * (N_ * C_ / 4);
  hipLaunchKernelGGL(gather_kernel, dim3((total4 + 255) / 256), dim3(256), 0, stream,
                     gpat, nb, (float*)d_out, TK);
}

// Round 12
// 295.993 us; speedup vs baseline: 1.4585x; 1.4585x over previous
//
#include <hip/hip_runtime.h>
#include <float.h>
#include <math.h>

#define B_ 16
#define N_ 128
#define C_ 768
#define G_ 2000
#define CK_ 100
#define ALPHA_ 0.6f
#define EPS_ 1e-12f

// A presplit fragment layout (per b): [kt(24)][j(4)][ks(2)][hi|lo(2)][lane(64)][8 bf16]
//   elem offset = b*196608 + kt*8192 + j*2048 + ks*1024 + hilo*512 + lane*8
#define ASTRIDE_B_ (N_ * C_ * 2)   // 196608 elems per b

typedef __attribute__((ext_vector_type(8))) short bf16x8;
typedef __attribute__((ext_vector_type(16))) float f32x16;

// ---------------- helpers ----------------
__device__ inline float wave_sum_lane0(float s) {
  #pragma unroll
  for (int off = 32; off > 0; off >>= 1) s += __shfl_down(s, off);
  return s;  // valid in lane 0
}
__device__ inline float wave_sum_all(float s) {
  #pragma unroll
  for (int off = 1; off < 64; off <<= 1) s += __shfl_xor(s, off);
  return s;
}

__device__ inline unsigned short bf16_rtn(float x) {
  unsigned u = __float_as_uint(x);
  u += 0x7fffu + ((u >> 16) & 1u);
  return (unsigned short)(u >> 16);
}
// RNE split (A path, validated R2/R10)
__device__ inline void split2(float x, unsigned short& h, unsigned short& l) {
  h = bf16_rtn(x);
  float r = x - __uint_as_float(((unsigned)h) << 16);
  l = bf16_rtn(r);
}
// RTZ split of 8 floats -> packed hi uint4 + lo uint4 (+ exact fp32 sq-sum) — validated R9
__device__ inline void tsplit8(const float4& v0, const float4& v1,
                               uint4& h, uint4& l, float& sq) {
  float f[8] = {v0.x, v0.y, v0.z, v0.w, v1.x, v1.y, v1.z, v1.w};
  unsigned hu[4], lu[4];
  #pragma unroll
  for (int p = 0; p < 4; ++p) {
    float x0 = f[2 * p], x1 = f[2 * p + 1];
    sq = fmaf(x0, x0, sq);
    sq = fmaf(x1, x1, sq);
    unsigned u0 = __float_as_uint(x0), u1 = __float_as_uint(x1);
    float r0 = x0 - __uint_as_float(u0 & 0xFFFF0000u);
    float r1 = x1 - __uint_as_float(u1 & 0xFFFF0000u);
    unsigned v0b = __float_as_uint(r0), v1b = __float_as_uint(r1);
    hu[p] = (u0 >> 16) | (u1 & 0xFFFF0000u);
    lu[p] = (v0b >> 16) | (v1b & 0xFFFF0000u);
  }
  h = make_uint4(hu[0], hu[1], hu[2], hu[3]);
  l = make_uint4(lu[0], lu[1], lu[2], lu[3]);
}

// ---------------- fused prep: cls cosine distances + A norm/split into fragment layout -----
// (verbatim from R10 — absmax-0 validated)
#define NCLSBLK_ (B_ * G_ / 4)
__global__ void prep_kernel(const float* __restrict__ gcls, const float* __restrict__ qcls,
                            const float* __restrict__ qp,
                            float* __restrict__ dall,
                            unsigned short* __restrict__ qsp) {
  int t = threadIdx.x;
  int lane = t & 63;
  if ((int)blockIdx.x < NCLSBLK_) {
    int id = ((int)blockIdx.x * 256 + t) >> 6;
    int b = id / G_, g = id - b * G_;
    const float4* gv = (const float4*)(gcls + (size_t)g * C_);
    const float4* qv = (const float4*)(qcls + (size_t)b * C_);
    float sgq = 0.f, sgg = 0.f, sqq = 0.f;
    #pragma unroll
    for (int i = 0; i < 3; ++i) {
      float4 x = gv[lane + 64 * i], y = qv[lane + 64 * i];
      sgq += x.x * y.x + x.y * y.y + x.z * y.z + x.w * y.w;
      sgg += x.x * x.x + x.y * x.y + x.z * x.z + x.w * x.w;
      sqq += y.x * y.x + y.y * y.y + y.z * y.z + y.w * y.w;
    }
    sgq = wave_sum_lane0(sgq);
    sgg = wave_sum_lane0(sgg);
    sqq = wave_sum_lane0(sqq);
    if (lane == 0) {
      float gi = 1.0f / fmaxf(sqrtf(sgg), EPS_);
      float qi = 1.0f / fmaxf(sqrtf(sqq), EPS_);
      dall[id] = sgq * gi * qi;
    }
  } else {
    int wid = (((int)blockIdx.x - NCLSBLK_) * 256 + t) >> 6;   // row id 0..B*N-1
    int b = wid >> 7, rr = wid & 127;
    int j = rr >> 5, l31p = rr & 31;
    const float* row = qp + (size_t)wid * C_;
    float4 x0 = *(const float4*)(row + lane * 8);
    float4 x1 = *(const float4*)(row + lane * 8 + 4);
    float4 x2 = make_float4(0.f, 0.f, 0.f, 0.f), x3 = x2;
    if (lane < 32) {
      x2 = *(const float4*)(row + 512 + lane * 8);
      x3 = *(const float4*)(row + 512 + lane * 8 + 4);
    }
    float s = x0.x * x0.x + x0.y * x0.y + x0.z * x0.z + x0.w * x0.w
            + x1.x * x1.x + x1.y * x1.y + x1.z * x1.z + x1.w * x1.w
            + x2.x * x2.x + x2.y * x2.y + x2.z * x2.z + x2.w * x2.w
            + x3.x * x3.x + x3.y * x3.y + x3.z * x3.z + x3.w * x3.w;
    s = wave_sum_all(s);
    float inv = 1.0f / fmaxf(sqrtf(s), EPS_);
    size_t bj = (size_t)b * ASTRIDE_B_ + (size_t)j * 2048;
    #pragma unroll
    for (int half = 0; half < 2; ++half) {
      if (half == 1 && lane >= 32) break;
      int c = half == 0 ? lane : 64 + lane;
      float4 v0 = half == 0 ? x0 : x2;
      float4 v1 = half == 0 ? x1 : x3;
      v0.x *= inv; v0.y *= inv; v0.z *= inv; v0.w *= inv;
      v1.x *= inv; v1.y *= inv; v1.z *= inv; v1.w *= inv;
      float f[8] = {v0.x, v0.y, v0.z, v0.w, v1.x, v1.y, v1.z, v1.w};
      unsigned short hh[8], ll[8];
      #pragma unroll
      for (int i = 0; i < 8; ++i) split2(f[i], hh[i], ll[i]);
      uint4 hq, lq;
      hq.x = (unsigned)hh[0] | ((unsigned)hh[1] << 16);
      hq.y = (unsigned)hh[2] | ((unsigned)hh[3] << 16);
      hq.z = (unsigned)hh[4] | ((unsigned)hh[5] << 16);
      hq.w = (unsigned)hh[6] | ((unsigned)hh[7] << 16);
      lq.x = (unsigned)ll[0] | ((unsigned)ll[1] << 16);
      lq.y = (unsigned)ll[2] | ((unsigned)ll[3] << 16);
      lq.z = (unsigned)ll[4] | ((unsigned)ll[5] << 16);
      lq.w = (unsigned)ll[6] | ((unsigned)ll[7] << 16);
      int kt = c >> 2, ks = (c >> 1) & 1, lh = c & 1;
      int lanef = lh * 32 + l31p;
      size_t off = bj + (size_t)kt * 8192 + (size_t)ks * 1024 + (size_t)lanef * 8;
      *(uint4*)(qsp + off) = hq;         // hi block
      *(uint4*)(qsp + off + 512) = lq;   // lo block
    }
  }
}

// ---------------- top-100 per sample via full bitonic sort of 2048 packed keys -------------
__global__ void top100_kernel(const float* __restrict__ dall, int* __restrict__ cls_idx,
                              float* __restrict__ dsel) {
  __shared__ unsigned long long s[2048];
  int b = blockIdx.x, t = threadIdx.x;
  for (int i = t; i < 2048; i += 256) {
    unsigned long long y = 0xFFFFFFFFFFFFFFFFull;
    if (i < G_) {
      unsigned u = __float_as_uint(dall[b * G_ + i]);
      unsigned key = (u & 0x80000000u) ? ~u : (u | 0x80000000u);
      y = ~(((unsigned long long)key << 32) | (unsigned long long)(0xFFFFFFFFu - (unsigned)i));
    }
    s[i] = y;
  }
  __syncthreads();
  for (int k = 2; k <= 2048; k <<= 1) {
    for (int j = k >> 1; j > 0; j >>= 1) {
      for (int i = t; i < 2048; i += 256) {
        int l = i ^ j;
        if (l > i) {
          unsigned long long a = s[i], c = s[l];
          bool up = ((i & k) == 0);
          if ((a > c) == up) { s[i] = c; s[l] = a; }
        }
      }
      __syncthreads();
    }
  }
  for (int it = t; it < CK_; it += 256) {
    unsigned long long x = ~s[it];
    int idx = (int)(0xFFFFFFFFu - (unsigned)(x & 0xFFFFFFFFull));
    unsigned key = (unsigned)(x >> 32);
    unsigned u = (key & 0x80000000u) ? (key & 0x7FFFFFFFu) : ~key;
    cls_idx[b * CK_ + it] = idx;
    dsel[b * CK_ + it] = __uint_as_float(u);
  }
}

// ---------------- EMD kernel: A fragments from global with even/odd REGISTER PREFETCH; -----
// B through double-buffered LDS (1 barrier/tile). LDS ops per block-tile: 96 -> 48.
__global__ __launch_bounds__(256, 2) void emd_kernel(
    const unsigned short* __restrict__ qsp,
    const float* __restrict__ gpat,
    const int* __restrict__ cls_idx, const float* __restrict__ dsel,
    float* __restrict__ dist) {
  __shared__ __align__(16) unsigned short sBhi[2][4096], sBlo[2][4096];
  float* red_row = (float*)&sBhi[0][0];     // [128][2] 1024 B (post-loop alias)
  float* red_col = (float*)&sBhi[0][512];   // [128][2] 1024 B
  float* bssf    = (float*)&sBhi[0][1024];  // [256]    1024 B
  float* binvf   = (float*)&sBhi[0][1536];  // [128]     512 B

  // XCD-aware swizzle: blocks sharing b land on one XCD.
  int r = blockIdx.x;
  int xc = r & 7;
  int q = r >> 3;                       // 0..199
  int b = 2 * xc + (q >= CK_ ? 1 : 0);
  int k = (q >= CK_) ? (q - CK_) : q;
  int blk = b * CK_ + k;
  int g = cls_idx[blk];

  const float* Bptr = gpat + (size_t)g * (N_ * C_);

  int t = threadIdx.x;
  int lane = t & 63, wv = t >> 6;
  int wr = wv >> 1, wc = wv & 1;
  int l31 = lane & 31, lhi = lane >> 5;

  // B staging: thread t -> row m_st = t>>1, K-halfslot (t&1)*16
  int m_st = t >> 1, half = t & 1;
  const float* bB = Bptr + (size_t)m_st * C_ + half * 16;
  int sw_st = (m_st >> 1) & 3;
  int e0 = m_st * 32 + (((2 * half + 0) ^ sw_st) << 3);
  int e1 = m_st * 32 + (((2 * half + 1) ^ sw_st) << 3);

  f32x16 acc00, acc01, acc10, acc11;
  #pragma unroll
  for (int e = 0; e < 16; ++e) { acc00[e] = 0.f; acc01[e] = 0.f; acc10[e] = 0.f; acc11[e] = 0.f; }

  // A fragment base (rows 64*wr..64*wr+63 in fragment order, contiguous per wave-load)
  const unsigned short* aB = qsp + (size_t)b * ASTRIDE_B_ + (size_t)(2 * wr) * 2048
                           + (size_t)lane * 8;

  int rB0 = 64 * wc + l31, rB1 = rB0 + 32;
  int swF = (l31 >> 1) & 3;

  const int NT = C_ / 32;                            // 24
  float bsq = 0.f;

  // B reg prefetch (2-deep): bx = even tiles, by = odd tiles
  float4 bx0, bx1, bx2, bx3, by0, by1, by2, by3;
  // A fragment regs, parity-named (X = even tiles, Y = odd tiles); [0..3]=ks0, [4..7]=ks1
  bf16x8 aX0, aX1, aX2, aX3, aX4, aX5, aX6, aX7;
  bf16x8 aY0, aY1, aY2, aY3, aY4, aY5, aY6, aY7;

#define LOAD_BX(T) { int oB = (T) * 32;                                       \
    bx0 = *(const float4*)(bB + oB);      bx1 = *(const float4*)(bB + oB + 4);\
    bx2 = *(const float4*)(bB + oB + 8);  bx3 = *(const float4*)(bB + oB + 12); }
#define LOAD_BY(T) { int oB = (T) * 32;                                       \
    by0 = *(const float4*)(bB + oB);      by1 = *(const float4*)(bB + oB + 4);\
    by2 = *(const float4*)(bB + oB + 8);  by3 = *(const float4*)(bB + oB + 12); }
#define LOAD_AX(T) { const unsigned short* ap = aB + (size_t)(T) * 8192;      \
    aX0 = *(const bf16x8*)(ap);          aX1 = *(const bf16x8*)(ap + 512);    \
    aX2 = *(const bf16x8*)(ap + 2048);   aX3 = *(const bf16x8*)(ap + 2560);   \
    aX4 = *(const bf16x8*)(ap + 1024);   aX5 = *(const bf16x8*)(ap + 1536);   \
    aX6 = *(const bf16x8*)(ap + 3072);   aX7 = *(const bf16x8*)(ap + 3584); }
#define LOAD_AY(T) { const unsigned short* ap = aB + (size_t)(T) * 8192;      \
    aY0 = *(const bf16x8*)(ap);          aY1 = *(const bf16x8*)(ap + 512);    \
    aY2 = *(const bf16x8*)(ap + 2048);   aY3 = *(const bf16x8*)(ap + 2560);   \
    aY4 = *(const bf16x8*)(ap + 1024);   aY5 = *(const bf16x8*)(ap + 1536);   \
    aY6 = *(const bf16x8*)(ap + 3072);   aY7 = *(const bf16x8*)(ap + 3584); }

#define STAGE(P, Bq0, Bq1, Bq2, Bq3) {                                        \
    uint4 h, l;                                                               \
    tsplit8(Bq0, Bq1, h, l, bsq);                                             \
    *(uint4*)&sBhi[P][e0] = h;  *(uint4*)&sBlo[P][e0] = l;                    \
    tsplit8(Bq2, Bq3, h, l, bsq);                                             \
    *(uint4*)&sBhi[P][e1] = h;  *(uint4*)&sBlo[P][e1] = l;                    \
  }

// MFMA order identical to validated R8/R9/R10 path: per ks, {hh, hl, lh} per quadrant.
#define MFMA_BODY(P, A0, A1, A2, A3, A4, A5, A6, A7) {                        \
    {                                                                         \
      int so = ((lhi ^ swF) << 3);                                            \
      bf16x8 bh0 = *(const bf16x8*)&sBhi[P][rB0 * 32 + so];                   \
      bf16x8 bl0 = *(const bf16x8*)&sBlo[P][rB0 * 32 + so];                   \
      bf16x8 bh1 = *(const bf16x8*)&sBhi[P][rB1 * 32 + so];                   \
      bf16x8 bl1 = *(const bf16x8*)&sBlo[P][rB1 * 32 + so];                   \
      acc00 = __builtin_amdgcn_mfma_f32_32x32x16_bf16(A0, bh0, acc00, 0, 0, 0);\
      acc00 = __builtin_amdgcn_mfma_f32_32x32x16_bf16(A0, bl0, acc00, 0, 0, 0);\
      acc00 = __builtin_amdgcn_mfma_f32_32x32x16_bf16(A1, bh0, acc00, 0, 0, 0);\
      acc01 = __builtin_amdgcn_mfma_f32_32x32x16_bf16(A0, bh1, acc01, 0, 0, 0);\
      acc01 = __builtin_amdgcn_mfma_f32_32x32x16_bf16(A0, bl1, acc01, 0, 0, 0);\
      acc01 = __builtin_amdgcn_mfma_f32_32x32x16_bf16(A1, bh1, acc01, 0, 0, 0);\
      acc10 = __builtin_amdgcn_mfma_f32_32x32x16_bf16(A2, bh0, acc10, 0, 0, 0);\
      acc10 = __builtin_amdgcn_mfma_f32_32x32x16_bf16(A2, bl0, acc10, 0, 0, 0);\
      acc10 = __builtin_amdgcn_mfma_f32_32x32x16_bf16(A3, bh0, acc10, 0, 0, 0);\
      acc11 = __builtin_amdgcn_mfma_f32_32x32x16_bf16(A2, bh1, acc11, 0, 0, 0);\
      acc11 = __builtin_amdgcn_mfma_f32_32x32x16_bf16(A2, bl1, acc11, 0, 0, 0);\
      acc11 = __builtin_amdgcn_mfma_f32_32x32x16_bf16(A3, bh1, acc11, 0, 0, 0);\
    }                                                                         \
    {                                                                         \
      int so = (((2 + lhi) ^ swF) << 3);                                      \
      bf16x8 bh0 = *(const bf16x8*)&sBhi[P][rB0 * 32 + so];                   \
      bf16x8 bl0 = *(const bf16x8*)&sBlo[P][rB0 * 32 + so];                   \
      bf16x8 bh1 = *(const bf16x8*)&sBhi[P][rB1 * 32 + so];                   \
      bf16x8 bl1 = *(const bf16x8*)&sBlo[P][rB1 * 32 + so];                   \
      acc00 = __builtin_amdgcn_mfma_f32_32x32x16_bf16(A4, bh0, acc00, 0, 0, 0);\
      acc00 = __builtin_amdgcn_mfma_f32_32x32x16_bf16(A4, bl0, acc00, 0, 0, 0);\
      acc00 = __builtin_amdgcn_mfma_f32_32x32x16_bf16(A5, bh0, acc00, 0, 0, 0);\
      acc01 = __builtin_amdgcn_mfma_f32_32x32x16_bf16(A4, bh1, acc01, 0, 0, 0);\
      acc01 = __builtin_amdgcn_mfma_f32_32x32x16_bf16(A4, bl1, acc01, 0, 0, 0);\
      acc01 = __builtin_amdgcn_mfma_f32_32x32x16_bf16(A5, bh1, acc01, 0, 0, 0);\
      acc10 = __builtin_amdgcn_mfma_f32_32x32x16_bf16(A6, bh0, acc10, 0, 0, 0);\
      acc10 = __builtin_amdgcn_mfma_f32_32x32x16_bf16(A6, bl0, acc10, 0, 0, 0);\
      acc10 = __builtin_amdgcn_mfma_f32_32x32x16_bf16(A7, bh0, acc10, 0, 0, 0);\
      acc11 = __builtin_amdgcn_mfma_f32_32x32x16_bf16(A6, bh1, acc11, 0, 0, 0);\
      acc11 = __builtin_amdgcn_mfma_f32_32x32x16_bf16(A6, bl1, acc11, 0, 0, 0);\
      acc11 = __builtin_amdgcn_mfma_f32_32x32x16_bf16(A7, bh1, acc11, 0, 0, 0);\
    }                                                                         \
  }

  // prologue: B 2-deep; A even/odd 1-tile-ahead; stage tile 0 into buf0
  LOAD_BX(0);
  LOAD_BY(1);
  LOAD_AX(0);
  STAGE(0, bx0, bx1, bx2, bx3);
  LOAD_BX(2);
  LOAD_AY(1);
  __syncthreads();

  for (int kt = 0; kt < NT; kt += 2) {
    // even phase: stage odd tile kt+1 -> buf1; MFMA even tile kt from buf0 + aX
    if (kt + 1 < NT) STAGE(1, by0, by1, by2, by3);
    if (kt + 3 < NT) LOAD_BY(kt + 3);
    MFMA_BODY(0, aX0, aX1, aX2, aX3, aX4, aX5, aX6, aX7);
    if (kt + 2 < NT) LOAD_AX(kt + 2);
    __syncthreads();
    // odd phase: stage even tile kt+2 -> buf0; MFMA odd tile kt+1 from buf1 + aY
    if (kt + 1 < NT) {
      if (kt + 2 < NT) STAGE(0, bx0, bx1, bx2, bx3);
      if (kt + 4 < NT) LOAD_BX(kt + 4);
      MFMA_BODY(1, aY0, aY1, aY2, aY3, aY4, aY5, aY6, aY7);
      if (kt + 3 < NT) LOAD_AY(kt + 3);
    }
    __syncthreads();
  }
#undef LOAD_BX
#undef LOAD_BY
#undef LOAD_AX
#undef LOAD_AY
#undef STAGE
#undef MFMA_BODY

  // gallery-patch inverse norms (exact fp32 sq-sums accumulated during staging)
  bssf[t] = bsq;
  __syncthreads();
  if (t < 128) {
    float s = bssf[2 * t] + bssf[2 * t + 1];
    binvf[t] = 1.0f / fmaxf(sqrtf(s), EPS_);
  }
  __syncthreads();
  float bi0 = binvf[64 * wc + l31];
  float bi1 = binvf[64 * wc + 32 + l31];

  // ---- row phase ----
  {
    float rm[16];
    #pragma unroll
    for (int e = 0; e < 16; ++e) rm[e] = fmaxf(acc00[e] * bi0, acc01[e] * bi1);
    #pragma unroll
    for (int msk = 1; msk <= 16; msk <<= 1)
      #pragma unroll
      for (int e = 0; e < 16; ++e) rm[e] = fmaxf(rm[e], __shfl_xor(rm[e], msk));
    if (l31 == 0) {
      #pragma unroll
      for (int e = 0; e < 16; ++e)
        red_row[(64 * wr + (e & 3) + 8 * (e >> 2) + 4 * lhi) * 2 + wc] = rm[e];
    }
  }
  {
    float rm[16];
    #pragma unroll
    for (int e = 0; e < 16; ++e) rm[e] = fmaxf(acc10[e] * bi0, acc11[e] * bi1);
    #pragma unroll
    for (int msk = 1; msk <= 16; msk <<= 1)
      #pragma unroll
      for (int e = 0; e < 16; ++e) rm[e] = fmaxf(rm[e], __shfl_xor(rm[e], msk));
    if (l31 == 0) {
      #pragma unroll
      for (int e = 0; e < 16; ++e)
        red_row[(64 * wr + 32 + (e & 3) + 8 * (e >> 2) + 4 * lhi) * 2 + wc] = rm[e];
    }
  }
  // ---- col phase ----
  {
    float cm0 = -FLT_MAX, cm1 = -FLT_MAX;
    #pragma unroll
    for (int e = 0; e < 16; ++e) {
      cm0 = fmaxf(cm0, fmaxf(acc00[e], acc10[e]));
      cm1 = fmaxf(cm1, fmaxf(acc01[e], acc11[e]));
    }
    cm0 = fmaxf(cm0, __shfl_xor(cm0, 32)) * bi0;
    cm1 = fmaxf(cm1, __shfl_xor(cm1, 32)) * bi1;
    if (lane < 32) {
      red_col[(64 * wc + lane) * 2 + wr] = cm0;
      red_col[(64 * wc + 32 + lane) * 2 + wr] = cm1;
    }
  }
  __syncthreads();
  if (t < 128)
    bssf[t] = fmaxf(red_row[2 * t], red_row[2 * t + 1]) +
              fmaxf(red_col[2 * t], red_col[2 * t + 1]);
  __syncthreads();
  if (t < 64) {
    float v = bssf[t] + bssf[t + 64];
    #pragma unroll
    for (int off = 32; off > 0; off >>= 1) v += __shfl_down(v, off);
    if (t == 0) {
      float emd = 0.5f * v * (1.0f / 128.0f);
      dist[blk] = ALPHA_ * dsel[blk] + (1.0f - ALPHA_) * emd;
    }
  }
}

// ---------------- final top-k (wave-parallel argmax) + cls mean ----------------
__global__ void sel10_kernel(const float* __restrict__ dist, const int* __restrict__ cls_idx,
                             const float* __restrict__ gcls, float* __restrict__ out_cls,
                             int* __restrict__ nb, int TK) {
  int b = blockIdx.x, t = threadIdx.x;
  __shared__ float v[128];
  __shared__ int snb[64];
  if (t < 128) v[t] = (t < CK_) ? dist[b * CK_ + t] : -FLT_MAX;
  __syncthreads();
  for (int j = 0; j < TK; ++j) {
    if (t < 64) {
      float v0 = v[t], v1 = v[t + 64];
      float bv; int bi;
      if (v0 >= v1) { bv = v0; bi = t; } else { bv = v1; bi = t + 64; }
      #pragma unroll
      for (int off = 1; off < 64; off <<= 1) {
        float ov = __shfl_xor(bv, off);
        int   oi = __shfl_xor(bi, off);
        if (ov > bv || (ov == bv && oi < bi)) { bv = ov; bi = oi; }
      }
      if (t == 0) {
        int gg = cls_idx[b * CK_ + bi];
        snb[j] = gg;
        nb[b * TK + j] = gg;
        v[bi] = -FLT_MAX;
      }
    }
    __syncthreads();
  }
  float invk = 1.0f / (float)TK;
  for (int c = t; c < C_; c += 256) {
    float s = 0.f;
    for (int j = 0; j < TK; ++j) s += gcls[(size_t)snb[j] * C_ + c];
    out_cls[(size_t)b * C_ + c] = s * invk;
  }
}

// ---------------- gather selected patches to output ----------------
__global__ void gather_kernel(const float* __restrict__ gpat, const int* __restrict__ nb,
                              float* __restrict__ out, int TK) {
  int i = blockIdx.x * blockDim.x + threadIdx.x;
  int per_vec = N_ * C_ / 4;       // float4s per gallery entry
  int per_b = TK * per_vec;
  int total = B_ * per_b;
  if (i >= total) return;
  int b = i / per_b;
  int r = i - b * per_b;
  int j = r / per_vec;
  int off = r - j * per_vec;
  int g = nb[b * TK + j];
  ((float4*)out)[i] = ((const float4*)gpat)[(size_t)g * per_vec + off];
}

extern "C" void kernel_launch(void* const* d_in, const int* in_sizes, int n_in,
                              void* d_out, int out_size, void* d_ws, size_t ws_size,
                              hipStream_t stream) {
  (void)in_sizes; (void)n_in; (void)ws_size;
  const float* qcls = (const float*)d_in[0];
  const float* qpat = (const float*)d_in[1];
  const float* gcls = (const float*)d_in[2];
  const float* gpat = (const float*)d_in[3];
  int TK = (out_size / B_ - C_) / (N_ * C_);  // = top_k (10)

  unsigned short* qsp = (unsigned short*)d_ws;               // B * 196608 (A presplit frags)
  float* dall  = (float*)(qsp + (size_t)B_ * ASTRIDE_B_);    // B*G
  float* dsel  = dall + B_ * G_;                             // B*CK
  float* dist  = dsel + B_ * CK_;                            // B*CK
  int* cls_idx = (int*)(dist + B_ * CK_);                    // B*CK
  int* nb      = cls_idx + B_ * CK_;                         // B*TK

  hipLaunchKernelGGL(prep_kernel, dim3(NCLSBLK_ + B_ * N_ / 4), dim3(256), 0, stream,
                     gcls, qcls, qpat, dall, qsp);
  hipLaunchKernelGGL(top100_kernel, dim3(B_), dim3(256), 0, stream, dall, cls_idx, dsel);
  hipLaunchKernelGGL(emd_kernel, dim3(B_ * CK_), dim3(256), 0, stream,
                     qsp, gpat, cls_idx, dsel, dist);
  float* out_cls = (float*)d_out + (size_t)B_ * TK * N_ * C_;
  hipLaunchKernelGGL(sel10_kernel, dim3(B_), dim3(256), 0, stream,
                     dist, cls_idx, gcls, out_cls, nb, TK);
  int total4 = B_ * TK * (N_ * C_ / 4);
  hipLaunchKernelGGL(gather_kernel, dim3((total4 + 255) / 256), dim3(256), 0, stream,
                     gpat, nb, (float*)d_out, TK);
}